// Round 9
// baseline (394.594 us; speedup 1.0000x reference)
//
#include <hip/hip_runtime.h>
#include <cstdint>

// ---------------------------------------------------------------------------
// PaddedSoftmaxSHCSA: y = softmax(mask(scale * (xW+b)_q @ (xW+b)_k^T)) @ (xW+b)_v
// T=4096, C=2048, NF=2048, 3*NF=6144. fp32 in/out, bf16 MFMA compute.
//
// Round 16 (= Round 15 resubmit after infra failure; logic re-audited:
// vmcnt queue trace, WAR/RAW, uniform barriers — all safe).
// T4 counted-vmcnt via ASYMMETRIC ring (one variable vs R7). R7 post-mortem:
// spill fixed (WRITE 49 MB) but active-block MfmaUtil 42%; P3 vmcnt(0) is the
// "drain-0" variant (m218: counted-vs-drain0 = +38%). Ring-2 both ops forces
// drain-0; ring-3 both = 192 KiB > 160. Fix: A ring-3 (96 KB) + B ring-2
// (64 KB) = 160 KiB. Per K-tile P0: stage B(kt+1) then A(kt+2); boundary
// waits vmcnt(4) -> A(kt+1)+B(kt+1) landed, A(kt+2) stays in flight. Never
// vmcnt(0) in the main loop. All else identical to R7: 256x256 cell, 8 waves
// of 128x64, acc[8][4], 4 phases {reads; BAR; 16 MFMA setprio; BAR}, 8-chunk
// XOR swizzle (0 conflicts), grids qkv 16x24 / sc 136 / pv 192.
// ---------------------------------------------------------------------------

#define T_DIM 4096
#define C_DIM 2048
#define NF    2048
#define N3    6144
#define NEGV  (-1e30f)

typedef __bf16 bf16x8 __attribute__((ext_vector_type(8)));
typedef __bf16 bf16x4 __attribute__((ext_vector_type(4)));
typedef float  f32x4  __attribute__((ext_vector_type(4)));

#define FENCE() asm volatile("" ::: "memory")
#define BARRIER() do { FENCE(); __builtin_amdgcn_s_barrier(); FENCE(); } while (0)

__device__ __forceinline__ void async_cp16(const void* g, void* l) {
    __builtin_amdgcn_global_load_lds(
        reinterpret_cast<const __attribute__((address_space(1))) unsigned int*>(
            reinterpret_cast<uintptr_t>(g)),
        reinterpret_cast<__attribute__((address_space(3))) unsigned int*>(
            reinterpret_cast<uintptr_t>(l)),
        16, 0, 0);
}

// ---------------- shared 256x256 cell GEMM core, asymmetric ring -----------
// C[m0..+256, n0..+256] += A @ B^T over kiters BK=64 tiles.
// As3: 3 slots x (256*64) bf16 (96 KB); Bs2: 2 slots (64 KB). 512 threads,
// 8 waves 2x4, per-wave 128x64, acc[8][4]. 4 phases/K-tile, 16 MFMA each.
// Stage at P0: B(kt+1) then A(kt+2); boundary wait vmcnt(4) (counted).
__device__ __forceinline__ void gemm256(const __bf16* A, const __bf16* B,
                                        int lda, int ldb, int m0, int n0,
                                        int kiters, __bf16* As3, __bf16* Bs2,
                                        f32x4 (&acc)[8][4]) {
    if (kiters <= 0) return;
    const int t    = threadIdx.x;        // 0..511
    const int wv   = t >> 6;             // wave 0..7
    const int lane = t & 63;
    const int srow = t >> 3;             // staging row 0..63 per issue
    const int scol = (((t & 7) ^ (srow & 7)) << 3);  // pre-swizzled src chunk
    const int wmo  = (wv >> 2) * 128;    // wave m offset 0/128
    const int wno  = (wv & 3) * 64;      // wave n offset 0/64/128/192
    const int lrow = lane & 15;
    const int kq   = lane >> 4;
    const int swz  = lrow & 7;
    const int rc0  = ((kq ^ swz) << 3);
    const int rc1  = (((kq | 4) ^ swz) << 3);

    const __bf16* ga = A + (size_t)(m0 + srow) * lda + scol;
    const __bf16* gb = B + (size_t)(n0 + srow) * ldb + scol;

    auto stA4 = [&](int kk, int s) {     // A tile kk -> slot s (4 issues)
        const __bf16* a = ga + kk * 64;
        __bf16* dst = As3 + s * 16384 + wv * 512;
#pragma unroll
        for (int j = 0; j < 4; ++j)
            async_cp16(a + (size_t)(64 * j) * lda, dst + j * 4096);
    };
    auto stB4 = [&](int kk, int s) {     // B tile kk -> slot s (4 issues)
        const __bf16* b2 = gb + kk * 64;
        __bf16* dst = Bs2 + s * 16384 + wv * 512;
#pragma unroll
        for (int j = 0; j < 4; ++j)
            async_cp16(b2 + (size_t)(64 * j) * ldb, dst + j * 4096);
    };
    auto loadA4 = [&](const __bf16* Ab, int mh, int rc, bf16x8 (&af)[4]) {
#pragma unroll
        for (int mi = 0; mi < 4; ++mi)
            af[mi] = *(const bf16x8*)
                &Ab[(wmo + mh * 64 + mi * 16 + lrow) * 64 + rc];
    };
    auto loadB4 = [&](const __bf16* Bb, int rc, bf16x8 (&bfr)[4]) {
#pragma unroll
        for (int ni = 0; ni < 4; ++ni)
            bfr[ni] = *(const bf16x8*)&Bb[(wno + ni * 16 + lrow) * 64 + rc];
    };

    bf16x8 af[4], bfr[4];

    // prologue: B(0), A(0), A(1) -> wait leaves A(1) in flight
    stB4(0, 0);
    stA4(0, 0);
    if (kiters > 1) {
        stA4(1, 1);
        asm volatile("s_waitcnt vmcnt(4)" ::: "memory");
    } else {
        asm volatile("s_waitcnt vmcnt(0)" ::: "memory");
    }
    BARRIER();

    int sa = 0, sb = 0;                  // current slots: kt%3, kt&1
    for (int kt = 0; kt < kiters; ++kt) {
        const __bf16* Ab = As3 + sa * 16384;
        const __bf16* Bb = Bs2 + sb * 16384;
        const int sa2 = (sa >= 1) ? sa - 1 : sa + 2;   // (kt+2)%3
        const bool pfB = (kt + 1 < kiters);
        const bool pfA = (kt + 2 < kiters);

        // P0: stage B(kt+1) [older] then A(kt+2) [newer]; reads (kh0,mh0)
        if (pfB) stB4(kt + 1, sb ^ 1);
        if (pfA) stA4(kt + 2, sa2);
        loadB4(Bb, rc0, bfr);
        loadA4(Ab, 0, rc0, af);
        BARRIER();
        __builtin_amdgcn_s_setprio(1);
#pragma unroll
        for (int mi = 0; mi < 4; ++mi)
#pragma unroll
            for (int ni = 0; ni < 4; ++ni)
                acc[mi][ni] = __builtin_amdgcn_mfma_f32_16x16x32_bf16(
                    af[mi], bfr[ni], acc[mi][ni], 0, 0, 0);
        __builtin_amdgcn_s_setprio(0);
        BARRIER();
        // P1: (kh0, mh1)
        loadA4(Ab, 1, rc0, af);
        BARRIER();
        __builtin_amdgcn_s_setprio(1);
#pragma unroll
        for (int mi = 0; mi < 4; ++mi)
#pragma unroll
            for (int ni = 0; ni < 4; ++ni)
                acc[4 + mi][ni] = __builtin_amdgcn_mfma_f32_16x16x32_bf16(
                    af[mi], bfr[ni], acc[4 + mi][ni], 0, 0, 0);
        __builtin_amdgcn_s_setprio(0);
        BARRIER();
        // P2: (kh1, mh0)
        loadB4(Bb, rc1, bfr);
        loadA4(Ab, 0, rc1, af);
        BARRIER();
        __builtin_amdgcn_s_setprio(1);
#pragma unroll
        for (int mi = 0; mi < 4; ++mi)
#pragma unroll
            for (int ni = 0; ni < 4; ++ni)
                acc[mi][ni] = __builtin_amdgcn_mfma_f32_16x16x32_bf16(
                    af[mi], bfr[ni], acc[mi][ni], 0, 0, 0);
        __builtin_amdgcn_s_setprio(0);
        BARRIER();
        // P3: (kh1, mh1); boundary wait COUNTED vmcnt(4) in steady state
        loadA4(Ab, 1, rc1, af);
        BARRIER();
        __builtin_amdgcn_s_setprio(1);
#pragma unroll
        for (int mi = 0; mi < 4; ++mi)
#pragma unroll
            for (int ni = 0; ni < 4; ++ni)
                acc[4 + mi][ni] = __builtin_amdgcn_mfma_f32_16x16x32_bf16(
                    af[mi], bfr[ni], acc[4 + mi][ni], 0, 0, 0);
        __builtin_amdgcn_s_setprio(0);
        if (pfA)       asm volatile("s_waitcnt vmcnt(4)" ::: "memory");
        else if (pfB)  asm volatile("s_waitcnt vmcnt(0)" ::: "memory");
        BARRIER();

        sa = (sa == 2) ? 0 : sa + 1;
        sb ^= 1;
    }
}

// per-thread epilogue coords for the 256x256 cell
#define EPI256()                                            \
    const int t = threadIdx.x, wv = t >> 6, lane = t & 63;  \
    const int wmo = (wv >> 2) * 128, wno = (wv & 3) * 64;   \
    const int rq = (lane >> 4) << 2, cn = lane & 15

// ---------------- 1. prep: cast x -> bf16  AND  transpose-cast W -----------
__global__ void prep_kernel(const float* __restrict__ x,
                            __bf16* __restrict__ xb,
                            const float* __restrict__ W,
                            __bf16* __restrict__ Wt) {
    if (blockIdx.x < 2048) {
        const int n4 = (T_DIM * C_DIM) / 4;
        const int stride = 2048 * 256;
        for (int i = blockIdx.x * 256 + threadIdx.x; i < n4; i += stride) {
            float4 v = ((const float4*)x)[i];
            bf16x4 o;
            o[0] = (__bf16)v.x; o[1] = (__bf16)v.y;
            o[2] = (__bf16)v.z; o[3] = (__bf16)v.w;
            ((bf16x4*)xb)[i] = o;
        }
        return;
    }
    __shared__ float tile[32][33];
    const int tb = blockIdx.x - 2048;
    const int bx = (tb % (N3 / 32)) * 32;  // W col / Wt row
    const int by = (tb / (N3 / 32)) * 32;  // W row / Wt col
    const int tx = threadIdx.x & 31, ty = threadIdx.x >> 5;  // (32,8)
#pragma unroll
    for (int i = 0; i < 32; i += 8)
        tile[ty + i][tx] = W[(size_t)(by + ty + i) * N3 + bx + tx];
    __syncthreads();
#pragma unroll
    for (int i = 0; i < 32; i += 8)
        Wt[(size_t)(bx + ty + i) * C_DIM + by + tx] = (__bf16)tile[tx][ty + i];
}

// ---------------- 3. QKV GEMM: 256x256 blocks, grid 16x24 ------------------
__global__ void __launch_bounds__(512)
qkv_gemm_kernel(const __bf16* __restrict__ xb, const __bf16* __restrict__ Wt,
                const float* __restrict__ bias, __bf16* __restrict__ qb,
                __bf16* __restrict__ kb, __bf16* __restrict__ vT) {
    __shared__ __bf16 As3[3 * 256 * 64];  // 96 KB
    __shared__ __bf16 Bs2[2 * 256 * 64];  // 64 KB
    f32x4 acc[8][4] = {};
    const int m0 = blockIdx.x * 256;
    const int by = blockIdx.y;           // 0..23
    const int n0 = by * 256;
    gemm256(xb, Wt, C_DIM, C_DIM, m0, n0, C_DIM / 64, As3, Bs2, acc);

    EPI256();
    if (by >= 16) {                      // v block: vT[col-4096][row]
#pragma unroll
        for (int mi = 0; mi < 8; ++mi)
#pragma unroll
            for (int ni = 0; ni < 4; ++ni) {
                int col = n0 + wno + ni * 16 + cn;
                float bv = bias[col];
                bf16x4 o;
#pragma unroll
                for (int r = 0; r < 4; ++r) o[r] = (__bf16)(acc[mi][ni][r] + bv);
                int row = m0 + wmo + mi * 16 + rq;
                *(bf16x4*)&vT[(size_t)(col - 2 * NF) * T_DIM + row] = o;
            }
    } else {
        __bf16* dst = (by < 8) ? qb : kb;
        const int coff = (by < 8) ? 0 : NF;
#pragma unroll
        for (int mi = 0; mi < 8; ++mi)
#pragma unroll
            for (int ni = 0; ni < 4; ++ni) {
                int col = n0 + wno + ni * 16 + cn;
                float bv = bias[col];
#pragma unroll
                for (int r = 0; r < 4; ++r) {
                    int row = m0 + wmo + mi * 16 + rq + r;
                    dst[(size_t)row * NF + (col - coff)] =
                        (__bf16)(acc[mi][ni][r] + bv);
                }
            }
    }
}

// ---------------- 4. S = scale * q @ k^T: triangular 256 tiles -------------
__global__ void __launch_bounds__(512)
sc_gemm_kernel(const __bf16* __restrict__ qb, const __bf16* __restrict__ kb,
               __bf16* __restrict__ S, const int* __restrict__ npadd_p) {
    int i = blockIdx.x;                  // 0..135 triangular
    int mt = (int)((sqrtf(8.0f * (float)i + 1.0f) - 1.0f) * 0.5f);
    while ((mt + 1) * (mt + 2) / 2 <= i) ++mt;
    while (mt * (mt + 1) / 2 > i) --mt;
    int nt = i - mt * (mt + 1) / 2;
    const int m0 = mt * 256, n0 = nt * 256;
    const int npadd = *npadd_p;
    if (m0 + 256 <= npadd || n0 + 256 <= npadd) return;  // fully masked

    __shared__ __bf16 As3[3 * 256 * 64];
    __shared__ __bf16 Bs2[2 * 256 * 64];
    f32x4 acc[8][4] = {};
    gemm256(qb, kb, NF, NF, m0, n0, NF / 64, As3, Bs2, acc);

    const float scale = 0.022097086912079608f;  // 1/sqrt(2048)
    EPI256();
#pragma unroll
    for (int mi = 0; mi < 8; ++mi)
#pragma unroll
        for (int ni = 0; ni < 4; ++ni) {
            int j = n0 + wno + ni * 16 + cn;
#pragma unroll
            for (int r = 0; r < 4; ++r) {
                int row = m0 + wmo + mi * 16 + rq + r;
                S[(size_t)row * T_DIM + j] = (__bf16)(acc[mi][ni][r] * scale);
            }
        }
}

// ---------------- 5. row softmax: one WAVE per row, no barriers ------------
__global__ void __launch_bounds__(256)
softmax_kernel(const __bf16* __restrict__ S, __bf16* __restrict__ P,
               const int* __restrict__ npadd_p) {
    const int wv = threadIdx.x >> 6, lane = threadIdx.x & 63;
    const int row = blockIdx.x * 4 + wv;
    const int npadd = *npadd_p;
    __bf16* prow = P + (size_t)row * T_DIM;

    if (row < npadd) {  // padding row: p == 0
        bf16x8 z = {};
#pragma unroll
        for (int c = 0; c < 8; ++c) ((bf16x8*)prow)[c * 64 + lane] = z;
        return;
    }

    const __bf16* srow = S + (size_t)row * T_DIM;
    float vals[64];
    float mx = NEGV;
#pragma unroll
    for (int c = 0; c < 8; ++c) {
        if (c * 512 > row) {  // wave-uniform skip
#pragma unroll
            for (int e = 0; e < 8; ++e) vals[c * 8 + e] = NEGV;
            continue;
        }
        int j0 = c * 512 + lane * 8;
        bf16x8 v = ((const bf16x8*)srow)[c * 64 + lane];
#pragma unroll
        for (int e = 0; e < 8; ++e) {
            float f = (j0 + e >= npadd && j0 + e <= row) ? (float)v[e] : NEGV;
            vals[c * 8 + e] = f;
            mx = fmaxf(mx, f);
        }
    }
#pragma unroll
    for (int o = 32; o > 0; o >>= 1) mx = fmaxf(mx, __shfl_xor(mx, o));

    float sm = 0.f;
#pragma unroll
    for (int k = 0; k < 64; ++k) {
        vals[k] = exp2f((vals[k] - mx) * 1.4426950408889634f);
        sm += vals[k];
    }
#pragma unroll
    for (int o = 32; o > 0; o >>= 1) sm += __shfl_xor(sm, o);
    float inv = 1.0f / sm;

#pragma unroll
    for (int c = 0; c < 8; ++c) {
        bf16x8 o;
#pragma unroll
        for (int e = 0; e < 8; ++e) o[e] = (__bf16)(vals[c * 8 + e] * inv);
        ((bf16x8*)prow)[c * 64 + lane] = o;
    }
}

// ---------------- 6. y = P @ V: 256 tiles, split-K for mt>=8 ---------------
__global__ void __launch_bounds__(512)
pv_gemm_kernel(const __bf16* __restrict__ P, const __bf16* __restrict__ vT,
               float* __restrict__ out, const int* __restrict__ npadd_p) {
    const int idx = blockIdx.x;
    const int kskip = *npadd_p >> 6;  // BK=64 tiles fully inside padding
    int mt, nt, start, iters;
    bool atomic_out;
    if (idx < 64) {
        mt = idx >> 3; nt = idx & 7;
        int ktt = (mt + 1) * 4 - kskip; if (ktt < 0) ktt = 0;
        start = kskip; iters = ktt; atomic_out = false;
    } else {
        int j = idx - 64;
        mt = 8 + ((j >> 3) & 7); nt = j & 7;
        int half = j >> 6;
        int ktt = (mt + 1) * 4 - kskip; if (ktt < 0) ktt = 0;
        int h0 = (ktt + 1) >> 1;
        start = kskip + (half ? h0 : 0);
        iters = half ? ktt - h0 : h0;
        atomic_out = true;
    }
    const int m0 = mt * 256, n0 = nt * 256;

    __shared__ __bf16 As3[3 * 256 * 64];
    __shared__ __bf16 Bs2[2 * 256 * 64];
    f32x4 acc[8][4] = {};
    gemm256(P + (size_t)start * 64, vT + (size_t)start * 64,
            T_DIM, T_DIM, m0, n0, iters, As3, Bs2, acc);

    EPI256();
#pragma unroll
    for (int mi = 0; mi < 8; ++mi)
#pragma unroll
        for (int ni = 0; ni < 4; ++ni) {
            int col = n0 + wno + ni * 16 + cn;
#pragma unroll
            for (int r = 0; r < 4; ++r) {
                int row = m0 + wmo + mi * 16 + rq + r;
                float* p = &out[(size_t)row * NF + col];
                if (atomic_out) unsafeAtomicAdd(p, acc[mi][ni][r]);
                else            *p = acc[mi][ni][r];
            }
        }
}

extern "C" void kernel_launch(void* const* d_in, const int* in_sizes, int n_in,
                              void* d_out, int out_size, void* d_ws,
                              size_t ws_size, hipStream_t stream) {
    const float* x = (const float*)d_in[0];
    const float* W = (const float*)d_in[1];
    const float* b = (const float*)d_in[2];
    const int* npadd = (const int*)d_in[3];
    float* out = (float*)d_out;

    char* ws = (char*)d_ws;
    // layout (120 MB used):
    __bf16* xb = (__bf16*)(ws);                          // 16 MB [0,16)
    __bf16* Wt = (__bf16*)(ws + (16ull << 20));          // 24 MB [16,40)
    __bf16* qb = (__bf16*)(ws + (40ull << 20));          // 16 MB [40,56)
    __bf16* kb = (__bf16*)(ws + (56ull << 20));          // 16 MB [56,72)
    __bf16* vT = (__bf16*)(ws + (72ull << 20));          // 16 MB [72,88)
    __bf16* S  = (__bf16*)(ws + (88ull << 20));          // 32 MB [88,120)
    __bf16* P  = (__bf16*)(ws + (40ull << 20));          // 32 MB reuse qb+kb

    // zero the atomic-accumulated half of out (rows 2048..4095)
    hipMemsetAsync(out + (size_t)2048 * NF, 0, (size_t)2048 * NF * 4, stream);

    prep_kernel<<<2048 + (N3 / 32) * (C_DIM / 32), 256, 0, stream>>>(x, xb, W, Wt);
    qkv_gemm_kernel<<<dim3(T_DIM / 256, N3 / 256), 512, 0, stream>>>(xb, Wt, b,
                                                                     qb, kb, vT);
    sc_gemm_kernel<<<136, 512, 0, stream>>>(qb, kb, S, npadd);
    softmax_kernel<<<T_DIM / 4, 256, 0, stream>>>(S, P, npadd);
    pv_gemm_kernel<<<192, 512, 0, stream>>>(P, vT, out, npadd);
}

// Round 10
// 349.923 us; speedup vs baseline: 1.1277x; 1.1277x over previous
//
#include <hip/hip_runtime.h>
#include <cstdint>

// ---------------------------------------------------------------------------
// PaddedSoftmaxSHCSA: y = softmax(mask(scale * (xW+b)_q @ (xW+b)_k^T)) @ (xW+b)_v
// T=4096, C=2048, NF=2048, 3*NF=6144. fp32 in/out, bf16 MFMA compute.
//
// Round 17: qkv = OVERLAPPED 256x256 cell (R5's quadrant-prefetch structure
// x R7's spill-free acc[8][4] geometry — the untested quadrant). Per K-tile:
// NO mid-tile barriers; quadrant q+1's ds_reads issue before quadrant q's
// MFMA cluster (frag double-buffer afA/afB/bfrA/bfrB = 64 VGPR; total ~225,
// fits 256). Compiler's counted lgkmcnt lets reads fly under MFMA. 2
// barriers/K-tile; vmcnt(0) at tile end is ~2000cy stale (counted-by-time,
// R7-vs-R9 showed drain==counted). Regs: acc 128 + frags 64 + addr ~30.
// R9 evidence: 4-phase lockstep = serial read+MFMA spans = 42% active util
// in BOTH drain and counted variants (T4 null) -> overlap, not waits.
// sc/pv: revert to measured-best 128^2 + R5 gemm_loop, grids 528/768
// (R9's 136/192 grids = 0.53/0.75 rounds under-filled; non-qkv 215->255).
// Keep: 8-chunk XOR swizzle (0 conflicts), wave-per-row softmax, prep fusion.
// ---------------------------------------------------------------------------

#define T_DIM 4096
#define C_DIM 2048
#define NF    2048
#define N3    6144
#define NEGV  (-1e30f)

typedef __bf16 bf16x8 __attribute__((ext_vector_type(8)));
typedef __bf16 bf16x4 __attribute__((ext_vector_type(4)));
typedef float  f32x4  __attribute__((ext_vector_type(4)));

#define FENCE() asm volatile("" ::: "memory")
#define BARRIER() do { FENCE(); __builtin_amdgcn_s_barrier(); FENCE(); } while (0)

__device__ __forceinline__ void async_cp16(const void* g, void* l) {
    __builtin_amdgcn_global_load_lds(
        reinterpret_cast<const __attribute__((address_space(1))) unsigned int*>(
            reinterpret_cast<uintptr_t>(g)),
        reinterpret_cast<__attribute__((address_space(3))) unsigned int*>(
            reinterpret_cast<uintptr_t>(l)),
        16, 0, 0);
}

// ---- 128x128-tile GEMM K-loop (sc/pv): BK=64, ring-2, reads-before-MFMA ---
__device__ __forceinline__ void gemm_loop(const __bf16* A, const __bf16* B,
                                          int lda, int ldb, int m0, int n0,
                                          int kiters, __bf16* As, __bf16* Bs,
                                          f32x4 (&acc)[4][4]) {
    if (kiters <= 0) return;
    const int t    = threadIdx.x;          // 0..255
    const int wv   = t >> 6;               // wave 0..3
    const int lane = t & 63;
    const int srow = t >> 3;               // staging row 0..31 (issue 0)
    const int scol = (((t & 7) ^ (srow & 7)) << 3);  // pre-swizzled src chunk
    const int wm   = (wv >> 1) << 6;       // wave m offset 0/64
    const int wn   = (wv & 1) << 6;        // wave n offset 0/64
    const int lrow = lane & 15;
    const int kq   = lane >> 4;            // logical chunk within k-step 0..3
    const int swz  = lrow & 7;             // 16/32/64 row offsets preserve &7
    const int rc0  = ((kq ^ swz) << 3);         // k-step 0: chunks 0..3
    const int rc1  = (((kq | 4) ^ swz) << 3);   // k-step 1: chunks 4..7

    const __bf16* ga = A + (size_t)(m0 + srow) * lda + scol;
    const __bf16* gb = B + (size_t)(n0 + srow) * ldb + scol;

    auto stage = [&](int kk, int s) {
#pragma unroll
        for (int i = 0; i < 4; ++i) {
            async_cp16(ga + kk * 64 + (size_t)(32 * i) * lda,
                       &As[s * 8192 + i * 2048 + wv * 512]);
            async_cp16(gb + kk * 64 + (size_t)(32 * i) * ldb,
                       &Bs[s * 8192 + i * 2048 + wv * 512]);
        }
    };
    auto loadF = [&](const __bf16* Ab, const __bf16* Bb, int rc,
                     bf16x8 (&af)[4], bf16x8 (&bfr)[4]) {
#pragma unroll
        for (int mi = 0; mi < 4; ++mi)
            af[mi] = *(const bf16x8*)&Ab[(wm + mi * 16 + lrow) * 64 + rc];
#pragma unroll
        for (int ni = 0; ni < 4; ++ni)
            bfr[ni] = *(const bf16x8*)&Bb[(wn + ni * 16 + lrow) * 64 + rc];
    };
    auto mfma16 = [&](bf16x8 (&af)[4], bf16x8 (&bfr)[4]) {
        __builtin_amdgcn_s_setprio(1);
#pragma unroll
        for (int mi = 0; mi < 4; ++mi)
#pragma unroll
            for (int ni = 0; ni < 4; ++ni)
                acc[mi][ni] = __builtin_amdgcn_mfma_f32_16x16x32_bf16(
                    af[mi], bfr[ni], acc[mi][ni], 0, 0, 0);
        __builtin_amdgcn_s_setprio(0);
    };

    bf16x8 af[4], bfr[4];

    stage(0, 0);
    asm volatile("s_waitcnt vmcnt(0)" ::: "memory");
    BARRIER();

    for (int kk = 0; kk < kiters; ++kk) {
        const int b = kk & 1;
        const __bf16* Ab = &As[b * 8192];
        const __bf16* Bb = &Bs[b * 8192];
        const bool pf = (kk + 1 < kiters);
        if (pf) stage(kk + 1, b ^ 1);
        loadF(Ab, Bb, rc0, af, bfr);
        mfma16(af, bfr);
        loadF(Ab, Bb, rc1, af, bfr);   // issues while kh0 MFMA drains
        mfma16(af, bfr);
        asm volatile("s_waitcnt vmcnt(0)" ::: "memory");  // counted-by-time
        BARRIER();
    }
}

// ---- 256x256 cell (qkv): quadrant-prefetch OVERLAP, 2 barriers/K-tile -----
__device__ __forceinline__ void gemm256(const __bf16* A, const __bf16* B,
                                        int lda, int ldb, int m0, int n0,
                                        int kiters, __bf16* As, __bf16* Bs,
                                        f32x4 (&acc)[8][4]) {
    if (kiters <= 0) return;
    const int t    = threadIdx.x;        // 0..511
    const int wv   = t >> 6;             // wave 0..7
    const int lane = t & 63;
    const int srow = t >> 3;             // staging row 0..63 per issue
    const int scol = (((t & 7) ^ (srow & 7)) << 3);  // pre-swizzled src chunk
    const int wmo  = (wv >> 2) * 128;    // wave m offset 0/128
    const int wno  = (wv & 3) * 64;      // wave n offset 0/64/128/192
    const int lrow = lane & 15;
    const int kq   = lane >> 4;
    const int swz  = lrow & 7;
    const int rc0  = ((kq ^ swz) << 3);
    const int rc1  = (((kq | 4) ^ swz) << 3);

    const __bf16* ga = A + (size_t)(m0 + srow) * lda + scol;
    const __bf16* gb = B + (size_t)(n0 + srow) * ldb + scol;

    auto stA4 = [&](int kk, int s) {
        const __bf16* a = ga + kk * 64;
        __bf16* dst = As + s * 16384 + wv * 512;
#pragma unroll
        for (int j = 0; j < 4; ++j)
            async_cp16(a + (size_t)(64 * j) * lda, dst + j * 4096);
    };
    auto stB4 = [&](int kk, int s) {
        const __bf16* b2 = gb + kk * 64;
        __bf16* dst = Bs + s * 16384 + wv * 512;
#pragma unroll
        for (int j = 0; j < 4; ++j)
            async_cp16(b2 + (size_t)(64 * j) * ldb, dst + j * 4096);
    };
    auto loadA4 = [&](const __bf16* Ab, int mh, int rc, bf16x8 (&af)[4]) {
#pragma unroll
        for (int mi = 0; mi < 4; ++mi)
            af[mi] = *(const bf16x8*)
                &Ab[(wmo + mh * 64 + mi * 16 + lrow) * 64 + rc];
    };
    auto loadB4 = [&](const __bf16* Bb, int rc, bf16x8 (&bfr)[4]) {
#pragma unroll
        for (int ni = 0; ni < 4; ++ni)
            bfr[ni] = *(const bf16x8*)&Bb[(wno + ni * 16 + lrow) * 64 + rc];
    };
    auto mfma16 = [&](bf16x8 (&af)[4], bf16x8 (&bfr)[4], int mh) {
        __builtin_amdgcn_s_setprio(1);
#pragma unroll
        for (int mi = 0; mi < 4; ++mi)
#pragma unroll
            for (int ni = 0; ni < 4; ++ni)
                acc[mh * 4 + mi][ni] = __builtin_amdgcn_mfma_f32_16x16x32_bf16(
                    af[mi], bfr[ni], acc[mh * 4 + mi][ni], 0, 0, 0);
        __builtin_amdgcn_s_setprio(0);
    };

    bf16x8 afA[4], afB[4], bfrA[4], bfrB[4];

    stA4(0, 0); stB4(0, 0);
    asm volatile("s_waitcnt vmcnt(0)" ::: "memory");
    BARRIER();
    loadB4(Bs, rc0, bfrA);               // Q0 frags of kt=0
    loadA4(As, 0, rc0, afA);

    for (int kt = 0; kt < kiters; ++kt) {
        const int b = kt & 1;
        const __bf16* Ab = As + b * 16384;
        const __bf16* Bb = Bs + b * 16384;
        const bool pf = (kt + 1 < kiters);
        if (pf) { stA4(kt + 1, b ^ 1); stB4(kt + 1, b ^ 1); }
        loadA4(Ab, 1, rc0, afB);         // Q1 reads hide under Q0 MFMA
        mfma16(afA, bfrA, 0);            // Q0 (kh0, mh0)
        loadB4(Bb, rc1, bfrB);           // kh1 reads hide under Q1 MFMA
        loadA4(Ab, 0, rc1, afA);
        mfma16(afB, bfrA, 1);            // Q1 (kh0, mh1)
        loadA4(Ab, 1, rc1, afB);         // Q3 reads hide under Q2 MFMA
        mfma16(afA, bfrB, 0);            // Q2 (kh1, mh0)
        mfma16(afB, bfrB, 1);            // Q3 (kh1, mh1)
        asm volatile("s_waitcnt vmcnt(0)" ::: "memory");  // ~2000cy stale
        BARRIER();                       // admit b^1; reads of b consumed
        if (pf) {                        // next-tile Q0 prefetch (post-BAR)
            loadB4(Bs + (b ^ 1) * 16384, rc0, bfrA);
            loadA4(As + (b ^ 1) * 16384, 0, rc0, afA);
        }
    }
}

// epilogue helpers
#define EPILOG_SETUP()                                     \
    const int t = threadIdx.x, wv = t >> 6, lane = t & 63; \
    const int wm = (wv >> 1) << 6, wn = (wv & 1) << 6;     \
    const int rq = (lane >> 4) << 2, cn = lane & 15
#define EPI256()                                            \
    const int t = threadIdx.x, wv = t >> 6, lane = t & 63;  \
    const int wmo = (wv >> 2) * 128, wno = (wv & 3) * 64;   \
    const int rq = (lane >> 4) << 2, cn = lane & 15

// ---------------- 1. prep: cast x -> bf16  AND  transpose-cast W -----------
__global__ void prep_kernel(const float* __restrict__ x,
                            __bf16* __restrict__ xb,
                            const float* __restrict__ W,
                            __bf16* __restrict__ Wt) {
    if (blockIdx.x < 2048) {
        const int n4 = (T_DIM * C_DIM) / 4;
        const int stride = 2048 * 256;
        for (int i = blockIdx.x * 256 + threadIdx.x; i < n4; i += stride) {
            float4 v = ((const float4*)x)[i];
            bf16x4 o;
            o[0] = (__bf16)v.x; o[1] = (__bf16)v.y;
            o[2] = (__bf16)v.z; o[3] = (__bf16)v.w;
            ((bf16x4*)xb)[i] = o;
        }
        return;
    }
    __shared__ float tile[32][33];
    const int tb = blockIdx.x - 2048;
    const int bx = (tb % (N3 / 32)) * 32;  // W col / Wt row
    const int by = (tb / (N3 / 32)) * 32;  // W row / Wt col
    const int tx = threadIdx.x & 31, ty = threadIdx.x >> 5;  // (32,8)
#pragma unroll
    for (int i = 0; i < 32; i += 8)
        tile[ty + i][tx] = W[(size_t)(by + ty + i) * N3 + bx + tx];
    __syncthreads();
#pragma unroll
    for (int i = 0; i < 32; i += 8)
        Wt[(size_t)(bx + ty + i) * C_DIM + by + tx] = (__bf16)tile[tx][ty + i];
}

// ---------------- 3. QKV GEMM: overlapped 256x256 cell, grid 16x24 ---------
__global__ void __launch_bounds__(512)
qkv_gemm_kernel(const __bf16* __restrict__ xb, const __bf16* __restrict__ Wt,
                const float* __restrict__ bias, __bf16* __restrict__ qb,
                __bf16* __restrict__ kb, __bf16* __restrict__ vT) {
    __shared__ __bf16 As[2 * 256 * 64];  // 64 KB
    __shared__ __bf16 Bs[2 * 256 * 64];  // 64 KB
    f32x4 acc[8][4] = {};
    const int m0 = blockIdx.x * 256;
    const int by = blockIdx.y;           // 0..23
    const int n0 = by * 256;
    gemm256(xb, Wt, C_DIM, C_DIM, m0, n0, C_DIM / 64, As, Bs, acc);

    EPI256();
    if (by >= 16) {                      // v block: vT[col-4096][row]
#pragma unroll
        for (int mi = 0; mi < 8; ++mi)
#pragma unroll
            for (int ni = 0; ni < 4; ++ni) {
                int col = n0 + wno + ni * 16 + cn;
                float bv = bias[col];
                bf16x4 o;
#pragma unroll
                for (int r = 0; r < 4; ++r) o[r] = (__bf16)(acc[mi][ni][r] + bv);
                int row = m0 + wmo + mi * 16 + rq;
                *(bf16x4*)&vT[(size_t)(col - 2 * NF) * T_DIM + row] = o;
            }
    } else {
        __bf16* dst = (by < 8) ? qb : kb;
        const int coff = (by < 8) ? 0 : NF;
#pragma unroll
        for (int mi = 0; mi < 8; ++mi)
#pragma unroll
            for (int ni = 0; ni < 4; ++ni) {
                int col = n0 + wno + ni * 16 + cn;
                float bv = bias[col];
#pragma unroll
                for (int r = 0; r < 4; ++r) {
                    int row = m0 + wmo + mi * 16 + rq + r;
                    dst[(size_t)row * NF + (col - coff)] =
                        (__bf16)(acc[mi][ni][r] + bv);
                }
            }
    }
}

// ---------------- 4. S = scale * q @ k^T: triangular 128 tiles -------------
__global__ void __launch_bounds__(256)
sc_gemm_kernel(const __bf16* __restrict__ qb, const __bf16* __restrict__ kb,
               __bf16* __restrict__ S, const int* __restrict__ npadd_p) {
    int i = blockIdx.x;
    int mt = (int)((sqrtf(8.0f * (float)i + 1.0f) - 1.0f) * 0.5f);
    while ((mt + 1) * (mt + 2) / 2 <= i) ++mt;
    while (mt * (mt + 1) / 2 > i) --mt;
    int nt = i - mt * (mt + 1) / 2;
    const int m0 = mt * 128, n0 = nt * 128;
    const int npadd = *npadd_p;
    if (m0 + 128 <= npadd || n0 + 128 <= npadd) return;  // fully masked

    __shared__ __bf16 As[2 * 128 * 64];
    __shared__ __bf16 Bs[2 * 128 * 64];
    f32x4 acc[4][4] = {};
    gemm_loop(qb, kb, NF, NF, m0, n0, NF / 64, As, Bs, acc);

    const float scale = 0.022097086912079608f;  // 1/sqrt(2048)
    EPILOG_SETUP();
#pragma unroll
    for (int mi = 0; mi < 4; ++mi)
#pragma unroll
        for (int ni = 0; ni < 4; ++ni) {
            int j = n0 + wn + ni * 16 + cn;
#pragma unroll
            for (int r = 0; r < 4; ++r) {
                int row = m0 + wm + mi * 16 + rq + r;
                S[(size_t)row * T_DIM + j] = (__bf16)(acc[mi][ni][r] * scale);
            }
        }
}

// ---------------- 5. row softmax: one WAVE per row, no barriers ------------
__global__ void __launch_bounds__(256)
softmax_kernel(const __bf16* __restrict__ S, __bf16* __restrict__ P,
               const int* __restrict__ npadd_p) {
    const int wv = threadIdx.x >> 6, lane = threadIdx.x & 63;
    const int row = blockIdx.x * 4 + wv;
    const int npadd = *npadd_p;
    __bf16* prow = P + (size_t)row * T_DIM;

    if (row < npadd) {  // padding row: p == 0
        bf16x8 z = {};
#pragma unroll
        for (int c = 0; c < 8; ++c) ((bf16x8*)prow)[c * 64 + lane] = z;
        return;
    }

    const __bf16* srow = S + (size_t)row * T_DIM;
    float vals[64];
    float mx = NEGV;
#pragma unroll
    for (int c = 0; c < 8; ++c) {
        if (c * 512 > row) {  // wave-uniform skip
#pragma unroll
            for (int e = 0; e < 8; ++e) vals[c * 8 + e] = NEGV;
            continue;
        }
        int j0 = c * 512 + lane * 8;
        bf16x8 v = ((const bf16x8*)srow)[c * 64 + lane];
#pragma unroll
        for (int e = 0; e < 8; ++e) {
            float f = (j0 + e >= npadd && j0 + e <= row) ? (float)v[e] : NEGV;
            vals[c * 8 + e] = f;
            mx = fmaxf(mx, f);
        }
    }
#pragma unroll
    for (int o = 32; o > 0; o >>= 1) mx = fmaxf(mx, __shfl_xor(mx, o));

    float sm = 0.f;
#pragma unroll
    for (int k = 0; k < 64; ++k) {
        vals[k] = exp2f((vals[k] - mx) * 1.4426950408889634f);
        sm += vals[k];
    }
#pragma unroll
    for (int o = 32; o > 0; o >>= 1) sm += __shfl_xor(sm, o);
    float inv = 1.0f / sm;

#pragma unroll
    for (int c = 0; c < 8; ++c) {
        bf16x8 o;
#pragma unroll
        for (int e = 0; e < 8; ++e) o[e] = (__bf16)(vals[c * 8 + e] * inv);
        ((bf16x8*)prow)[c * 64 + lane] = o;
    }
}

// ---------------- 6. y = P @ V: 128 tiles, split-K for the deep tiles ------
__global__ void __launch_bounds__(256)
pv_gemm_kernel(const __bf16* __restrict__ P, const __bf16* __restrict__ vT,
               float* __restrict__ out, const int* __restrict__ npadd_p) {
    const int idx = blockIdx.x;
    const int kskip = *npadd_p >> 6;  // BK=64 tiles fully inside padding
    int mt, nt, start, iters;
    bool atomic_out;
    if (idx < 256) {
        mt = idx & 15; nt = idx >> 4;
        int kt = (mt + 1) * 2 - kskip; if (kt < 0) kt = 0;
        start = kskip; iters = kt; atomic_out = false;
    } else {
        int j = idx - 256;
        mt = 16 + (j & 15); nt = (j >> 4) & 15;
        int half = j >> 8;
        int kt = (mt + 1) * 2 - kskip; if (kt < 0) kt = 0;
        int h0 = (kt + 1) >> 1;
        start = kskip + (half ? h0 : 0);
        iters = half ? kt - h0 : h0;
        atomic_out = true;
    }
    const int m0 = mt * 128, n0 = nt * 128;

    __shared__ __bf16 As[2 * 128 * 64];
    __shared__ __bf16 Bs[2 * 128 * 64];
    f32x4 acc[4][4] = {};
    gemm_loop(P + (size_t)start * 64, vT + (size_t)start * 64,
              T_DIM, T_DIM, m0, n0, iters, As, Bs, acc);

    EPILOG_SETUP();
#pragma unroll
    for (int mi = 0; mi < 4; ++mi)
#pragma unroll
        for (int ni = 0; ni < 4; ++ni) {
            int col = n0 + wn + ni * 16 + cn;
#pragma unroll
            for (int r = 0; r < 4; ++r) {
                int row = m0 + wm + mi * 16 + rq + r;
                float* p = &out[(size_t)row * NF + col];
                if (atomic_out) unsafeAtomicAdd(p, acc[mi][ni][r]);
                else            *p = acc[mi][ni][r];
            }
        }
}

extern "C" void kernel_launch(void* const* d_in, const int* in_sizes, int n_in,
                              void* d_out, int out_size, void* d_ws,
                              size_t ws_size, hipStream_t stream) {
    const float* x = (const float*)d_in[0];
    const float* W = (const float*)d_in[1];
    const float* b = (const float*)d_in[2];
    const int* npadd = (const int*)d_in[3];
    float* out = (float*)d_out;

    char* ws = (char*)d_ws;
    // layout (120 MB used):
    __bf16* xb = (__bf16*)(ws);                          // 16 MB [0,16)
    __bf16* Wt = (__bf16*)(ws + (16ull << 20));          // 24 MB [16,40)
    __bf16* qb = (__bf16*)(ws + (40ull << 20));          // 16 MB [40,56)
    __bf16* kb = (__bf16*)(ws + (56ull << 20));          // 16 MB [56,72)
    __bf16* vT = (__bf16*)(ws + (72ull << 20));          // 16 MB [72,88)
    __bf16* S  = (__bf16*)(ws + (88ull << 20));          // 32 MB [88,120)
    __bf16* P  = (__bf16*)(ws + (40ull << 20));          // 32 MB reuse qb+kb

    // zero the atomic-accumulated half of out (rows 2048..4095)
    hipMemsetAsync(out + (size_t)2048 * NF, 0, (size_t)2048 * NF * 4, stream);

    prep_kernel<<<2048 + (N3 / 32) * (C_DIM / 32), 256, 0, stream>>>(x, xb, W, Wt);
    qkv_gemm_kernel<<<dim3(T_DIM / 256, N3 / 256), 512, 0, stream>>>(xb, Wt, b,
                                                                     qb, kb, vT);
    sc_gemm_kernel<<<528, 256, 0, stream>>>(qb, kb, S, npadd);
    softmax_kernel<<<T_DIM / 4, 256, 0, stream>>>(S, P, npadd);
    pv_gemm_kernel<<<768, 256, 0, stream>>>(P, vT, out, npadd);
}

// Round 12
// 323.022 us; speedup vs baseline: 1.2216x; 1.0833x over previous
//
#include <hip/hip_runtime.h>
#include <cstdint>

// ---------------------------------------------------------------------------
// PaddedSoftmaxSHCSA: y = softmax(mask(scale * (xW+b)_q @ (xW+b)_k^T)) @ (xW+b)_v
// T=4096, C=2048, NF=2048, 3*NF=6144. fp32 in/out, bf16 MFMA compute.
//
// Round 19 (= Round 18 resubmit after infra failure; audited: uniform
// barriers, bounds, alignment, reg budget — all safe).
// Rate x packing: ten rounds show block rate is 1600-1900 FLOP/cy for every
// reg-fitting structure; makespan = rate x grid packing. R10's overlap cell
// = best rate (1881 FLOP/cy) but 1.5-round grid; R4 = best total (330) on
// perfect packing. This round:
//  * qkv: 256x192 tile, grid 16x32 = 512 = 2.0 PERFECT rounds, R10-style
//    overlap (frag double-buffer, reads fly under MFMA, 1 barrier/K-tile).
//    acc[4][6]=96 + frags 80 = ~210 regs, no spill. Per-fragment q/k/v
//    routing (16-col fragments, boundaries 16-aligned). LDS 112 KB ring-2.
//  * sc/pv: R5's frag-double-buffered gemm_loop verbatim (best measured
//    rest = 215 us) at grids 528 / 768.
// Keep: 8-chunk XOR swizzle (0 conflicts), wave-per-row softmax, prep fusion.
// ---------------------------------------------------------------------------

#define T_DIM 4096
#define C_DIM 2048
#define NF    2048
#define N3    6144
#define NEGV  (-1e30f)

typedef __bf16 bf16x8 __attribute__((ext_vector_type(8)));
typedef __bf16 bf16x4 __attribute__((ext_vector_type(4)));
typedef float  f32x4  __attribute__((ext_vector_type(4)));

#define FENCE() asm volatile("" ::: "memory")
#define BARRIER() do { FENCE(); __builtin_amdgcn_s_barrier(); FENCE(); } while (0)

__device__ __forceinline__ void async_cp16(const void* g, void* l) {
    __builtin_amdgcn_global_load_lds(
        reinterpret_cast<const __attribute__((address_space(1))) unsigned int*>(
            reinterpret_cast<uintptr_t>(g)),
        reinterpret_cast<__attribute__((address_space(3))) unsigned int*>(
            reinterpret_cast<uintptr_t>(l)),
        16, 0, 0);
}

// ---- 128x128-tile GEMM K-loop (sc/pv): R5 frag-double-buffered overlap ----
__device__ __forceinline__ void gemm_loop(const __bf16* A, const __bf16* B,
                                          int lda, int ldb, int m0, int n0,
                                          int kiters, __bf16* As, __bf16* Bs,
                                          f32x4 (&acc)[4][4]) {
    if (kiters <= 0) return;
    const int t    = threadIdx.x;          // 0..255
    const int wv   = t >> 6;               // wave 0..3
    const int lane = t & 63;
    const int srow = t >> 3;               // staging row 0..31 (issue 0)
    const int scol = (((t & 7) ^ (srow & 7)) << 3);  // pre-swizzled src chunk
    const int wm   = (wv >> 1) << 6;       // wave m offset 0/64
    const int wn   = (wv & 1) << 6;        // wave n offset 0/64
    const int lrow = lane & 15;
    const int kq   = lane >> 4;            // logical chunk within k-step 0..3
    const int swz  = lrow & 7;             // 16/32/64 row offsets preserve &7
    const int rc0  = ((kq ^ swz) << 3);         // k-step 0: chunks 0..3
    const int rc1  = (((kq | 4) ^ swz) << 3);   // k-step 1: chunks 4..7

    const __bf16* ga = A + (size_t)(m0 + srow) * lda + scol;
    const __bf16* gb = B + (size_t)(n0 + srow) * ldb + scol;

    auto stage = [&](int kk, int s) {
#pragma unroll
        for (int i = 0; i < 4; ++i) {
            async_cp16(ga + kk * 64 + (size_t)(32 * i) * lda,
                       &As[s * 8192 + i * 2048 + wv * 512]);
            async_cp16(gb + kk * 64 + (size_t)(32 * i) * ldb,
                       &Bs[s * 8192 + i * 2048 + wv * 512]);
        }
    };
    auto loadF = [&](const __bf16* Ab, const __bf16* Bb, int rc,
                     bf16x8 (&af)[4], bf16x8 (&bfr)[4]) {
#pragma unroll
        for (int mi = 0; mi < 4; ++mi)
            af[mi] = *(const bf16x8*)&Ab[(wm + mi * 16 + lrow) * 64 + rc];
#pragma unroll
        for (int ni = 0; ni < 4; ++ni)
            bfr[ni] = *(const bf16x8*)&Bb[(wn + ni * 16 + lrow) * 64 + rc];
    };
    auto mfma16 = [&](bf16x8 (&af)[4], bf16x8 (&bfr)[4]) {
        __builtin_amdgcn_s_setprio(1);
#pragma unroll
        for (int mi = 0; mi < 4; ++mi)
#pragma unroll
            for (int ni = 0; ni < 4; ++ni)
                acc[mi][ni] = __builtin_amdgcn_mfma_f32_16x16x32_bf16(
                    af[mi], bfr[ni], acc[mi][ni], 0, 0, 0);
        __builtin_amdgcn_s_setprio(0);
    };

    bf16x8 af0[4], af1[4], bf0[4], bf1[4];

    stage(0, 0);
    asm volatile("s_waitcnt vmcnt(0)" ::: "memory");
    BARRIER();
    loadF(As, Bs, rc0, af0, bf0);   // half0 of kk=0

    for (int kk = 0; kk < kiters; ++kk) {
        const int b = kk & 1;
        const __bf16* Ab = &As[b * 8192];
        const __bf16* Bb = &Bs[b * 8192];
        const bool pf = (kk + 1 < kiters);
        if (pf) stage(kk + 1, b ^ 1);
        loadF(Ab, Bb, rc1, af1, bf1);   // half1 reads hide under half0 MFMA
        mfma16(af0, bf0);
        mfma16(af1, bf1);
        asm volatile("s_waitcnt vmcnt(0)" ::: "memory");  // counted-by-time
        BARRIER();
        if (pf)
            loadF(&As[(b ^ 1) * 8192], &Bs[(b ^ 1) * 8192], rc0, af0, bf0);
    }
}

// ---------------- 1. prep: cast x -> bf16  AND  transpose-cast W -----------
__global__ void prep_kernel(const float* __restrict__ x,
                            __bf16* __restrict__ xb,
                            const float* __restrict__ W,
                            __bf16* __restrict__ Wt) {
    if (blockIdx.x < 2048) {
        const int n4 = (T_DIM * C_DIM) / 4;
        const int stride = 2048 * 256;
        for (int i = blockIdx.x * 256 + threadIdx.x; i < n4; i += stride) {
            float4 v = ((const float4*)x)[i];
            bf16x4 o;
            o[0] = (__bf16)v.x; o[1] = (__bf16)v.y;
            o[2] = (__bf16)v.z; o[3] = (__bf16)v.w;
            ((bf16x4*)xb)[i] = o;
        }
        return;
    }
    __shared__ float tile[32][33];
    const int tb = blockIdx.x - 2048;
    const int bx = (tb % (N3 / 32)) * 32;  // W col / Wt row
    const int by = (tb / (N3 / 32)) * 32;  // W row / Wt col
    const int tx = threadIdx.x & 31, ty = threadIdx.x >> 5;  // (32,8)
#pragma unroll
    for (int i = 0; i < 32; i += 8)
        tile[ty + i][tx] = W[(size_t)(by + ty + i) * N3 + bx + tx];
    __syncthreads();
#pragma unroll
    for (int i = 0; i < 32; i += 8)
        Wt[(size_t)(bx + ty + i) * C_DIM + by + tx] = (__bf16)tile[tx][ty + i];
}

// epilogue helper for 128x128 cell
#define EPILOG_SETUP()                                     \
    const int t = threadIdx.x, wv = t >> 6, lane = t & 63; \
    const int wm = (wv >> 1) << 6, wn = (wv & 1) << 6;     \
    const int rq = (lane >> 4) << 2, cn = lane & 15

// ---------------- 3. QKV GEMM: 256x192 overlap cell, grid 16x32 = 2 rounds -
__global__ void __launch_bounds__(512)
qkv_gemm_kernel(const __bf16* __restrict__ xb, const __bf16* __restrict__ Wt,
                const float* __restrict__ bias, __bf16* __restrict__ qb,
                __bf16* __restrict__ kb, __bf16* __restrict__ vT) {
    __shared__ __bf16 As[2][256 * 64];   // 64 KB
    __shared__ __bf16 Bs[2][192 * 64];   // 48 KB

    const int t    = threadIdx.x;        // 0..511
    const int wv   = t >> 6;             // wave 0..7
    const int lane = t & 63;
    const int srow = t >> 3;             // staging row 0..63 per issue
    const int scol = (((t & 7) ^ (srow & 7)) << 3);  // pre-swizzled src chunk
    const int m0   = blockIdx.x * 256;   // 16 m-tiles
    const int n0   = blockIdx.y * 192;   // 32 n-tiles
    const int wmo  = (wv & 3) * 64;      // wave m offset 0/64/128/192
    const int wno  = (wv >> 2) * 96;     // wave n offset 0/96
    const int lrow = lane & 15;
    const int kq   = lane >> 4;
    const int swz  = lrow & 7;
    const int rc0  = ((kq ^ swz) << 3);
    const int rc1  = (((kq | 4) ^ swz) << 3);

    const __bf16* ga = xb + (size_t)(m0 + srow) * C_DIM + scol;
    const __bf16* gb = Wt + (size_t)(n0 + srow) * C_DIM + scol;

    f32x4 acc[4][6] = {};

    auto stage = [&](int kt, int s) {    // A 4 issues + B 3 issues
        const __bf16* a  = ga + kt * 64;
        const __bf16* b2 = gb + kt * 64;
#pragma unroll
        for (int j = 0; j < 4; ++j)
            async_cp16(a + (size_t)(64 * j) * C_DIM, &As[s][j * 4096 + wv * 512]);
#pragma unroll
        for (int j = 0; j < 3; ++j)
            async_cp16(b2 + (size_t)(64 * j) * C_DIM, &Bs[s][j * 4096 + wv * 512]);
    };
    auto loadF = [&](const __bf16* Ab, const __bf16* Bb, int rc,
                     bf16x8 (&af)[4], bf16x8 (&bfr)[6]) {
#pragma unroll
        for (int mi = 0; mi < 4; ++mi)
            af[mi] = *(const bf16x8*)&Ab[(wmo + mi * 16 + lrow) * 64 + rc];
#pragma unroll
        for (int ni = 0; ni < 6; ++ni)
            bfr[ni] = *(const bf16x8*)&Bb[(wno + ni * 16 + lrow) * 64 + rc];
    };
    auto mfma24 = [&](bf16x8 (&af)[4], bf16x8 (&bfr)[6]) {
        __builtin_amdgcn_s_setprio(1);
#pragma unroll
        for (int mi = 0; mi < 4; ++mi)
#pragma unroll
            for (int ni = 0; ni < 6; ++ni)
                acc[mi][ni] = __builtin_amdgcn_mfma_f32_16x16x32_bf16(
                    af[mi], bfr[ni], acc[mi][ni], 0, 0, 0);
        __builtin_amdgcn_s_setprio(0);
    };

    bf16x8 afA[4], afB[4];
    bf16x8 bfrA[6], bfrB[6];
    constexpr int KT = C_DIM / 64;  // 32

    stage(0, 0);
    asm volatile("s_waitcnt vmcnt(0)" ::: "memory");
    BARRIER();
    loadF(As[0], Bs[0], rc0, afA, bfrA);   // kh0 frags of kt=0

    for (int kt = 0; kt < KT; ++kt) {
        const int b = kt & 1;
        const bool pf = (kt + 1 < KT);
        if (pf) stage(kt + 1, b ^ 1);          // fills hide under MFMA
        loadF(As[b], Bs[b], rc1, afB, bfrB);   // kh1 reads under kh0 MFMA
        mfma24(afA, bfrA);                     // kh0
        mfma24(afB, bfrB);                     // kh1
        asm volatile("s_waitcnt vmcnt(0)" ::: "memory");  // ~1 tile stale
        BARRIER();                             // admit b^1; reads of b done
        if (pf) loadF(As[b ^ 1], Bs[b ^ 1], rc0, afA, bfrA);
    }

    // epilogue: per-fragment q/k/v routing (16-col fragments; 2048/4096
    // are 16-aligned so each fragment lies entirely in one region).
    const int rq = (lane >> 4) << 2, cn = lane & 15;
#pragma unroll
    for (int mi = 0; mi < 4; ++mi)
#pragma unroll
        for (int ni = 0; ni < 6; ++ni) {
            int col = n0 + wno + ni * 16 + cn;
            float bv = bias[col];
            if (col >= 2 * NF) {
                bf16x4 o;
#pragma unroll
                for (int r = 0; r < 4; ++r) o[r] = (__bf16)(acc[mi][ni][r] + bv);
                int row = m0 + wmo + mi * 16 + rq;
                *(bf16x4*)&vT[(size_t)(col - 2 * NF) * T_DIM + row] = o;
            } else {
#pragma unroll
                for (int r = 0; r < 4; ++r) {
                    int row = m0 + wmo + mi * 16 + rq + r;
                    float val = acc[mi][ni][r] + bv;
                    if (col < NF)
                        qb[(size_t)row * NF + col] = (__bf16)val;
                    else
                        kb[(size_t)row * NF + (col - NF)] = (__bf16)val;
                }
            }
        }
}

// ---------------- 4. S = scale * q @ k^T: triangular 128 tiles -------------
__global__ void __launch_bounds__(256)
sc_gemm_kernel(const __bf16* __restrict__ qb, const __bf16* __restrict__ kb,
               __bf16* __restrict__ S, const int* __restrict__ npadd_p) {
    int i = blockIdx.x;
    int mt = (int)((sqrtf(8.0f * (float)i + 1.0f) - 1.0f) * 0.5f);
    while ((mt + 1) * (mt + 2) / 2 <= i) ++mt;
    while (mt * (mt + 1) / 2 > i) --mt;
    int nt = i - mt * (mt + 1) / 2;
    const int m0 = mt * 128, n0 = nt * 128;
    const int npadd = *npadd_p;
    if (m0 + 128 <= npadd || n0 + 128 <= npadd) return;  // fully masked

    __shared__ __bf16 As[2 * 128 * 64];
    __shared__ __bf16 Bs[2 * 128 * 64];
    f32x4 acc[4][4] = {};
    gemm_loop(qb, kb, NF, NF, m0, n0, NF / 64, As, Bs, acc);

    const float scale = 0.022097086912079608f;  // 1/sqrt(2048)
    EPILOG_SETUP();
#pragma unroll
    for (int mi = 0; mi < 4; ++mi)
#pragma unroll
        for (int ni = 0; ni < 4; ++ni) {
            int j = n0 + wn + ni * 16 + cn;
#pragma unroll
            for (int r = 0; r < 4; ++r) {
                int row = m0 + wm + mi * 16 + rq + r;
                S[(size_t)row * T_DIM + j] = (__bf16)(acc[mi][ni][r] * scale);
            }
        }
}

// ---------------- 5. row softmax: one WAVE per row, no barriers ------------
__global__ void __launch_bounds__(256)
softmax_kernel(const __bf16* __restrict__ S, __bf16* __restrict__ P,
               const int* __restrict__ npadd_p) {
    const int wv = threadIdx.x >> 6, lane = threadIdx.x & 63;
    const int row = blockIdx.x * 4 + wv;
    const int npadd = *npadd_p;
    __bf16* prow = P + (size_t)row * T_DIM;

    if (row < npadd) {  // padding row: p == 0
        bf16x8 z = {};
#pragma unroll
        for (int c = 0; c < 8; ++c) ((bf16x8*)prow)[c * 64 + lane] = z;
        return;
    }

    const __bf16* srow = S + (size_t)row * T_DIM;
    float vals[64];
    float mx = NEGV;
#pragma unroll
    for (int c = 0; c < 8; ++c) {
        if (c * 512 > row) {  // wave-uniform skip
#pragma unroll
            for (int e = 0; e < 8; ++e) vals[c * 8 + e] = NEGV;
            continue;
        }
        int j0 = c * 512 + lane * 8;
        bf16x8 v = ((const bf16x8*)srow)[c * 64 + lane];
#pragma unroll
        for (int e = 0; e < 8; ++e) {
            float f = (j0 + e >= npadd && j0 + e <= row) ? (float)v[e] : NEGV;
            vals[c * 8 + e] = f;
            mx = fmaxf(mx, f);
        }
    }
#pragma unroll
    for (int o = 32; o > 0; o >>= 1) mx = fmaxf(mx, __shfl_xor(mx, o));

    float sm = 0.f;
#pragma unroll
    for (int k = 0; k < 64; ++k) {
        vals[k] = exp2f((vals[k] - mx) * 1.4426950408889634f);
        sm += vals[k];
    }
#pragma unroll
    for (int o = 32; o > 0; o >>= 1) sm += __shfl_xor(sm, o);
    float inv = 1.0f / sm;

#pragma unroll
    for (int c = 0; c < 8; ++c) {
        bf16x8 o;
#pragma unroll
        for (int e = 0; e < 8; ++e) o[e] = (__bf16)(vals[c * 8 + e] * inv);
        ((bf16x8*)prow)[c * 64 + lane] = o;
    }
}

// ---------------- 6. y = P @ V: 128 tiles, split-K for the deep tiles ------
__global__ void __launch_bounds__(256)
pv_gemm_kernel(const __bf16* __restrict__ P, const __bf16* __restrict__ vT,
               float* __restrict__ out, const int* __restrict__ npadd_p) {
    const int idx = blockIdx.x;
    const int kskip = *npadd_p >> 6;  // BK=64 tiles fully inside padding
    int mt, nt, start, iters;
    bool atomic_out;
    if (idx < 256) {
        mt = idx & 15; nt = idx >> 4;
        int kt = (mt + 1) * 2 - kskip; if (kt < 0) kt = 0;
        start = kskip; iters = kt; atomic_out = false;
    } else {
        int j = idx - 256;
        mt = 16 + (j & 15); nt = (j >> 4) & 15;
        int half = j >> 8;
        int kt = (mt + 1) * 2 - kskip; if (kt < 0) kt = 0;
        int h0 = (kt + 1) >> 1;
        start = kskip + (half ? h0 : 0);
        iters = half ? kt - h0 : h0;
        atomic_out = true;
    }
    const int m0 = mt * 128, n0 = nt * 128;

    __shared__ __bf16 As[2 * 128 * 64];
    __shared__ __bf16 Bs[2 * 128 * 64];
    f32x4 acc[4][4] = {};
    gemm_loop(P + (size_t)start * 64, vT + (size_t)start * 64,
              T_DIM, T_DIM, m0, n0, iters, As, Bs, acc);

    EPILOG_SETUP();
#pragma unroll
    for (int mi = 0; mi < 4; ++mi)
#pragma unroll
        for (int ni = 0; ni < 4; ++ni) {
            int col = n0 + wn + ni * 16 + cn;
#pragma unroll
            for (int r = 0; r < 4; ++r) {
                int row = m0 + wm + mi * 16 + rq + r;
                float* p = &out[(size_t)row * NF + col];
                if (atomic_out) unsafeAtomicAdd(p, acc[mi][ni][r]);
                else            *p = acc[mi][ni][r];
            }
        }
}

extern "C" void kernel_launch(void* const* d_in, const int* in_sizes, int n_in,
                              void* d_out, int out_size, void* d_ws,
                              size_t ws_size, hipStream_t stream) {
    const float* x = (const float*)d_in[0];
    const float* W = (const float*)d_in[1];
    const float* b = (const float*)d_in[2];
    const int* npadd = (const int*)d_in[3];
    float* out = (float*)d_out;

    char* ws = (char*)d_ws;
    // layout (120 MB used):
    __bf16* xb = (__bf16*)(ws);                          // 16 MB [0,16)
    __bf16* Wt = (__bf16*)(ws + (16ull << 20));          // 24 MB [16,40)
    __bf16* qb = (__bf16*)(ws + (40ull << 20));          // 16 MB [40,56)
    __bf16* kb = (__bf16*)(ws + (56ull << 20));          // 16 MB [56,72)
    __bf16* vT = (__bf16*)(ws + (72ull << 20));          // 16 MB [72,88)
    __bf16* S  = (__bf16*)(ws + (88ull << 20));          // 32 MB [88,120)
    __bf16* P  = (__bf16*)(ws + (40ull << 20));          // 32 MB reuse qb+kb

    // zero the atomic-accumulated half of out (rows 2048..4095)
    hipMemsetAsync(out + (size_t)2048 * NF, 0, (size_t)2048 * NF * 4, stream);

    prep_kernel<<<2048 + (N3 / 32) * (C_DIM / 32), 256, 0, stream>>>(x, xb, W, Wt);
    qkv_gemm_kernel<<<dim3(T_DIM / 256, N3 / 192), 512, 0, stream>>>(xb, Wt, b,
                                                                     qb, kb, vT);
    sc_gemm_kernel<<<528, 256, 0, stream>>>(qb, kb, S, npadd);
    softmax_kernel<<<T_DIM / 4, 256, 0, stream>>>(S, P, npadd);
    pv_gemm_kernel<<<768, 256, 0, stream>>>(P, vT, out, npadd);
}